// Round 4
// baseline (376.286 us; speedup 1.0000x reference)
//
#include <hip/hip_runtime.h>

typedef float f2 __attribute__((ext_vector_type(2)));
typedef _Float16 h2 __attribute__((ext_vector_type(2)));

__device__ __forceinline__ f2 fma2(f2 a, f2 b, f2 c) { return __builtin_elementwise_fma(a, b, c); }
__device__ __forceinline__ float sigm(float x) { float e = __expf(-x); return __builtin_amdgcn_rcpf(1.f + e); }

// quad_perm DPP: ctrl must be a literal
#define DPPQ(x, ctrl) __int_as_float(__builtin_amdgcn_mov_dpp(__float_as_int(x), (ctrl), 0xF, 0xF, true))
#define DPP_XOR1 0xB1  /* [1,0,3,2] */
#define DPP_XOR2 0x4E  /* [2,3,0,1] */

#if defined(__has_builtin)
#if __has_builtin(__builtin_amdgcn_fdot2)
#define FDOT2(a, b, c) __builtin_amdgcn_fdot2((a), (b), (c), false)
#endif
#endif
#ifndef FDOT2
#define FDOT2(a, b, c) ((c) + (float)(a)[0] * (float)(b)[0] + (float)(a)[1] * (float)(b)[1])
#endif

__device__ __forceinline__ h2 bch2(unsigned u) { union { unsigned u; h2 h; } x; x.u = u; return x.h; }

#define B_ 64
#define L_ 512
#define T_ 50
#define H_ 100
#define XGN (B_ * L_ * 400)   // half elements per direction of xg scratch

// ---------------- xg GEMM: gate pre-activations from inputs, all steps (fp16 out) ----------------
__global__ __launch_bounds__(256, 2) void xg_gemm(
    const int* __restrict__ ids, const float* __restrict__ tokt,
    const float* __restrict__ wihf, const float* __restrict__ wihb,
    _Float16* __restrict__ xg)
{
    const int blk = blockIdx.x, dir = blk >> 10, rest = blk & 1023;
    const int b = rest >> 4, lc = rest & 15, l0 = lc * 32;
    const int tid = threadIdx.x, k_raw = tid >> 1, r = tid & 1;
    const int k = (k_raw < 100) ? k_raw : 99;
    const bool act = tid < 200;
    const int rowA = r * 100 + k, rowB = 200 + r * 100 + k;
    const float* wih = dir ? wihb : wihf;

    f2 wA2[25], wB2[25];
#pragma unroll
    for (int j = 0; j < 25; ++j) {
        wA2[j] = *(const f2*)&wih[rowA * T_ + 2 * j];
        wB2[j] = *(const f2*)&wih[rowB * T_ + 2 * j];
    }

    _Float16* xgd = xg + (size_t)dir * XGN;
    for (int p = 0; p < 32; ++p) {
        int l = l0 + p;
        int id = ids[b * L_ + l];                    // uniform -> s_load
        const float* xr = tokt + (size_t)id * T_;    // uniform row
        f2 aA{0.f, 0.f}, aB{0.f, 0.f};
#pragma unroll
        for (int j = 0; j < 25; ++j) {
            f2 xv = f2{xr[2 * j], xr[2 * j + 1]};    // uniform scalar loads
            aA = fma2(wA2[j], xv, aA);
            aB = fma2(wB2[j], xv, aB);
        }
        int idx = dir ? (L_ - 1 - l) : l;            // step-ordered store
        _Float16* o = xgd + ((size_t)b * L_ + idx) * 400;
        if (act) { o[rowA] = (_Float16)(aA.x + aA.y); o[rowB] = (_Float16)(aB.x + aB.y); }
    }
}

// ---------------- BiLSTM recurrence v4: quad-per-unit, fp16 dot2, low pressure ----------------
// 512 threads. Quad kq owns unit k; lane rq holds 4 gate rows over h-seg [25rq,25rq+25)
// as 13 half2 (26 VGPR). h kept in LDS as fp16, 40-half padded segments (conflict-free).
// xg read per-step directly from global (fp16) with 1-step register prefetch. No xg LDS.
__global__ __launch_bounds__(512, 2) void lstm4(
    const _Float16* __restrict__ xg,
    const float* __restrict__ whhf, const float* __restrict__ bihf, const float* __restrict__ bhhf,
    const float* __restrict__ whhb, const float* __restrict__ bihb, const float* __restrict__ bhhb,
    float* __restrict__ out)
{
    __shared__ __align__(16) _Float16 hbuf[2][160];  // 4 segs x 40 halfs (25 used, 15 pad=0)

    const int blk = blockIdx.x, b = blk >> 1, dir = blk & 1, tid = threadIdx.x;
    const float* whh = dir ? whhb : whhf;
    const float* bih = dir ? bihb : bihf;
    const float* bhh = dir ? bhhb : bhhf;
    const _Float16* xgd = xg + (size_t)dir * XGN + (size_t)b * (L_ * 400);

    const int kq = tid >> 2, rq = tid & 3;
    const int k = (kq < 100) ? kq : 99;              // clamp idle quads
    const bool act = (kq < 100);
    const int row_g = rq * 100 + k;                  // gate row owned after transpose
    const int hoff = (k / 25) * 40 + (k % 25);       // padded h slot for unit k
    const int seg = rq * 25;

    // weights: w[r][j] = half2{W_hh[r*100+k][seg+2j], [seg+2j+1]}, pair 12 = {w24, 0}
    h2 w[4][13];
#pragma unroll
    for (int r = 0; r < 4; ++r) {
        const float* wr = whh + (size_t)(r * 100 + k) * 100 + seg;
#pragma unroll
        for (int j = 0; j < 12; ++j) w[r][j] = h2{(_Float16)wr[2 * j], (_Float16)wr[2 * j + 1]};
        w[r][12] = h2{(_Float16)wr[24], (_Float16)0.f};
    }
#pragma unroll
    for (int r = 0; r < 4; ++r)
#pragma unroll
        for (int j = 0; j < 13; ++j)
            asm volatile("" : "+v"(w[r][j]));        // pin loaded values

    const float bias = bih[row_g] + bhh[row_g];
    const float ascale = (rq == 2) ? 2.f : 1.f;      // tanh via 2*sigm(2x)-1 for gate g

    if (tid < 160) { hbuf[0][tid] = (_Float16)0.f; hbuf[1][tid] = (_Float16)0.f; }
    __syncthreads();

    float c = 0.f;
    float xv = (float)xgd[row_g];                    // step 0 gate input
    for (int s = 0; s < L_; ++s) {
        const int par = s & 1;
        float xv_n = (s + 1 < L_) ? (float)xgd[(size_t)(s + 1) * 400 + row_g] : 0.f;  // prefetch

        // h segment: 3 x b128 + 1 x b32 (26 halfs), broadcast + conflict-free
        const _Float16* hb = &hbuf[par][rq * 40];
        uint4 q0 = *(const uint4*)(hb);
        uint4 q1 = *(const uint4*)(hb + 8);
        uint4 q2 = *(const uint4*)(hb + 16);
        unsigned u12 = *(const unsigned*)(hb + 24);
        h2 p[13];
        p[0] = bch2(q0.x); p[1] = bch2(q0.y); p[2] = bch2(q0.z); p[3] = bch2(q0.w);
        p[4] = bch2(q1.x); p[5] = bch2(q1.y); p[6] = bch2(q1.z); p[7] = bch2(q1.w);
        p[8] = bch2(q2.x); p[9] = bch2(q2.y); p[10] = bch2(q2.z); p[11] = bch2(q2.w);
        p[12] = bch2(u12);

        float a0 = 0.f, a1 = 0.f, a2 = 0.f, a3 = 0.f;
#pragma unroll
        for (int j = 0; j < 13; ++j) {
            a0 = FDOT2(w[0][j], p[j], a0);
            a1 = FDOT2(w[1][j], p[j], a1);
            a2 = FDOT2(w[2][j], p[j], a2);
            a3 = FDOT2(w[3][j], p[j], a3);
        }

        // transpose-reduce over the quad: lane rq <- full dot of gate row rq
        float s0 = a0 + DPPQ(a0, DPP_XOR2);
        float s1 = a1 + DPPQ(a1, DPP_XOR2);
        float s2 = a2 + DPPQ(a2, DPP_XOR2);
        float s3 = a3 + DPPQ(a3, DPP_XOR2);
        float sA = (rq & 2) ? s2 : s0;
        float sB = (rq & 2) ? s3 : s1;
        float fA = DPPQ(sA, DPP_XOR1), fB = DPPQ(sB, DPP_XOR1);
        float tot = (rq & 1) ? (sB + fB) : (sA + fA);

        float prea = tot + xv + bias;
        float aa = sigm(ascale * prea);
        float a = (rq == 2) ? (2.f * aa - 1.f) : aa;   // 0:σ(i) 1:σ(f) 2:tanh(g) 3:σ(o)

        float bsw = DPPQ(a, DPP_XOR2);                 // 0:tanh(g) 1:σ(o) 2:σ(i) 3:σ(f)
        float t = (rq == 1) ? (a * c) : (a * bsw);     // lane0: i*g ; lane1: f*c
        float u = DPPQ(t, DPP_XOR1);
        float cn = t + u;                              // lanes 0,1: correct new c
        c = cn;
        float th = 2.f * sigm(2.f * cn) - 1.f;         // tanh(c)
        float hv = bsw * th;                           // lane1: o * tanh(c)

        if (act && rq == 1) {
            hbuf[par ^ 1][hoff] = (_Float16)hv;
            int l = dir ? (L_ - 1 - s) : s;
            out[((size_t)b * L_ + l) * 204 + (dir ? 104 : 0) + k] = hv;
        }
        xv = xv_n;
        __syncthreads();
    }
}

// ---------------- Fallback BiLSTM (used when ws too small) ----------------
__global__ __launch_bounds__(256, 1) void lstm_fb(
    const int* __restrict__ ids, const float* __restrict__ tokt,
    const float* __restrict__ wihf, const float* __restrict__ whhf,
    const float* __restrict__ bihf, const float* __restrict__ bhhf,
    const float* __restrict__ wihb, const float* __restrict__ whhb,
    const float* __restrict__ bihb, const float* __restrict__ bhhb,
    float* __restrict__ out)
{
    __shared__ __align__(16) float xbuf[2][16][64];
    __shared__ __align__(16) float hbuf[2][100];
    const int blk = blockIdx.x;
    const int b = blk >> 1, dir = blk & 1;
    const int tid = threadIdx.x;
    const float* wih = dir ? wihb : wihf;
    const float* whh = dir ? whhb : whhf;
    const float* bih = dir ? bihb : bihf;
    const float* bhh = dir ? bhhb : bhhf;
    const int k_raw = tid >> 1, r = tid & 1;
    const int k = (k_raw < 100) ? k_raw : 99;
    const bool wr = (tid < 200) && (r == 1);
    const int rowA = (r ? 100 : 0) + k;
    const int rowB = (r ? 300 : 200) + k;
    f2 wiA[26], wiB[26], whA[50], whB[50];
#pragma unroll
    for (int j = 0; j < 25; ++j) {
        wiA[j] = *(const f2*)&wih[rowA * T_ + 2 * j];
        wiB[j] = *(const f2*)&wih[rowB * T_ + 2 * j];
    }
    wiA[25] = f2{0.f, 0.f}; wiB[25] = f2{0.f, 0.f};
#pragma unroll
    for (int j = 0; j < 50; ++j) {
        whA[j] = *(const f2*)&whh[rowA * H_ + 2 * j];
        whB[j] = *(const f2*)&whh[rowB * H_ + 2 * j];
    }
    const float biasA = bih[rowA] + bhh[rowA];
    const float biasB = bih[rowB] + bhh[rowB];
    const int ids_base = b * L_;
    float pre[4];
#pragma unroll
    for (int i = 0; i < 4; ++i) {
        int e = tid + i * 256; int sl = e >> 6, j = e & 63;
        int l = dir ? (L_ - 1 - sl) : sl;
        int id = ids[ids_base + l];
        int jj = (j < T_) ? j : 0;
        float v = tokt[id * T_ + jj];
        pre[i] = (j < T_) ? v : 0.f;
    }
#pragma unroll
    for (int i = 0; i < 4; ++i) { int e = tid + i * 256; xbuf[0][e >> 6][e & 63] = pre[i]; }
#pragma unroll
    for (int i = 0; i < 4; ++i) {
        int e = tid + i * 256; int sl = e >> 6, j = e & 63;
        int s = 16 + sl;
        int l = dir ? (L_ - 1 - s) : s;
        int id = ids[ids_base + l];
        int jj = (j < T_) ? j : 0;
        float v = tokt[id * T_ + jj];
        pre[i] = (j < T_) ? v : 0.f;
    }
    if (tid < 100) hbuf[0][tid] = 0.f;
    __syncthreads();
    float c = 0.f;
    for (int s = 0; s < L_; ++s) {
        const int cb = (s >> 4) & 1, sl = s & 15, par = s & 1;
        const float* xrow = &xbuf[cb][sl][0];
        const float* hrow = &hbuf[par][0];
        f2 aA = f2{0.f, 0.f}, aB = f2{0.f, 0.f};
#pragma unroll
        for (int j = 0; j < 25; ++j) {
            float4 hv = *(const float4*)&hrow[4 * j];
            aA = fma2(whA[2 * j], f2{hv.x, hv.y}, aA);
            aA = fma2(whA[2 * j + 1], f2{hv.z, hv.w}, aA);
            aB = fma2(whB[2 * j], f2{hv.x, hv.y}, aB);
            aB = fma2(whB[2 * j + 1], f2{hv.z, hv.w}, aB);
        }
#pragma unroll
        for (int j = 0; j < 13; ++j) {
            float4 xv = *(const float4*)&xrow[4 * j];
            aA = fma2(wiA[2 * j], f2{xv.x, xv.y}, aA);
            aB = fma2(wiB[2 * j], f2{xv.x, xv.y}, aB);
            aA = fma2(wiA[2 * j + 1], f2{xv.z, xv.w}, aA);
            aB = fma2(wiB[2 * j + 1], f2{xv.z, xv.w}, aB);
        }
        float pA = biasA + aA.x + aA.y;
        float pB = biasB + aB.x + aB.y;
        float sA = sigm(pA);
        float inB = r ? pB : 2.f * pB;
        float sB = sigm(inB);
        float gB = r ? sB : 2.f * sB - 1.f;
        float t0 = r ? sA * c : sA * gB;
        float t1 = DPPQ(t0, DPP_XOR1);
        float cn = t0 + t1; c = cn;
        float th = 2.f * sigm(2.f * cn) - 1.f;
        float hv_ = gB * th;
        if (wr) {
            hbuf[par ^ 1][k] = hv_;
            int l = dir ? (L_ - 1 - s) : s;
            out[((size_t)b * L_ + l) * 204 + (dir ? 104 : 0) + k] = hv_;
        }
        if (sl == 15) {
            int nc = (s >> 4) + 1;
            if (nc < 32) {
#pragma unroll
                for (int i = 0; i < 4; ++i) { int e = tid + i * 256; xbuf[nc & 1][e >> 6][e & 63] = pre[i]; }
                if (nc + 1 < 32) {
#pragma unroll
                    for (int i = 0; i < 4; ++i) {
                        int e = tid + i * 256; int sl2 = e >> 6, j = e & 63;
                        int s2 = (nc + 1) * 16 + sl2;
                        int l2 = dir ? (L_ - 1 - s2) : s2;
                        int id = ids[ids_base + l2];
                        int jj = (j < T_) ? j : 0;
                        float v = tokt[id * T_ + jj];
                        pre[i] = (j < T_) ? v : 0.f;
                    }
                }
            }
        }
        __syncthreads();
    }
}

// ---------------- Attention v3: 16-l blocks, >=2 resident/CU, row-copy gathers ----------------
__global__ __launch_bounds__(256, 2) void attn3(
    const float* __restrict__ lex, const int* __restrict__ pids,
    const int* __restrict__ bmes, const int* __restrict__ lmask,
    const float* __restrict__ pint, const float* __restrict__ wp,
    const float* __restrict__ bp, float* __restrict__ out)
{
    __shared__ __align__(16) float hid[16 * 100];     // 6.4 KB
    __shared__ __align__(16) float catl[16 * 426];    // 27.3 KB, p-stride 426 (bank spread)
    __shared__ __align__(16) float vv[16 * 110];      // 7.0 KB
    __shared__ float wts[64];

    const int b = blockIdx.x >> 5, ch = blockIdx.x & 31, l0 = ch * 16;
    const int tid = threadIdx.x;
    const size_t bl0 = (size_t)b * L_ + l0;

    // W_proj column fcol (104 = bias row) register-resident
    const int fcol = tid & 127, ph = tid >> 7;
    f2 wc[50];
    if (fcol < 104) {
#pragma unroll
        for (int j = 0; j < 50; ++j)
            wc[j] = f2{wp[(2 * j) * 104 + fcol], wp[(2 * j + 1) * 104 + fcol]};
    } else if (fcol == 104) {
#pragma unroll
        for (int j = 0; j < 50; ++j) wc[j] = f2{bp[2 * j], bp[2 * j + 1]};
    } else {
#pragma unroll
        for (int j = 0; j < 50; ++j) wc[j] = f2{0.f, 0.f};
    }
#pragma unroll
    for (int j = 0; j < 50; ++j) asm volatile("" : "+v"(wc[j]));

    // hidden = h_f + h_b; finalize out[...,0:100]
    for (int e = tid; e < 1600; e += 256) {
        int p = e / 100, q = e % 100; size_t bl = bl0 + p;
        float sv = out[bl * 204 + q] + out[bl * 204 + 104 + q];
        hid[p * 100 + q] = sv; out[bl * 204 + q] = sv;
    }
    // bmes one-hot
    if (tid < 64) {
        int p = tid >> 2, w = tid & 3;
        int bm = bmes[(bl0 + p) * 4 + w];
        float* cb = &catl[p * 426 + w * 106];
        cb[0] = (bm == 0) ? 1.f : 0.f; cb[1] = (bm == 1) ? 1.f : 0.f;
        cb[2] = (bm == 2) ? 1.f : 0.f; cb[3] = (bm == 3) ? 1.f : 0.f;
    }
    // lexicon 50-float rows: fully coalesced
    for (int e = tid; e < 3200; e += 256) {
        int pr = e / 50, f = e % 50;
        int p = pr >> 2, w = pr & 3;
        catl[p * 426 + w * 106 + 4 + f] = lex[((bl0 + p) * 4 + w) * 50 + f];
    }
    // pinyin rows: quad-per-row copy (row-contiguous gather)
    {
        int pr = tid >> 2, q4 = tid & 3;
        int p = pr >> 2, w = pr & 3;
        int pid = pids[(bl0 + p) * 4 + w];
        const float* src = pint + (size_t)pid * 50;
        float* dst = &catl[p * 426 + w * 106 + 54];
        int j0 = q4 * 13, n = (q4 == 3) ? 11 : 13;
        for (int j = 0; j < n; ++j) dst[j0 + j] = src[j0 + j];
    }
    __syncthreads();

    // v[p][fcol] = col_fcol(W_proj) . hid[p]  (hid reads broadcast)
    if (fcol < 105) {
#pragma unroll
        for (int pp = 0; pp < 8; ++pp) {
            int p = ph * 8 + pp;
            const float4* h4 = (const float4*)&hid[p * 100];
            f2 a{0.f, 0.f};
#pragma unroll
            for (int j = 0; j < 25; ++j) {
                float4 hv = h4[j];
                a = fma2(wc[2 * j],     f2{hv.x, hv.y}, a);
                a = fma2(wc[2 * j + 1], f2{hv.z, hv.w}, a);
            }
            vv[p * 110 + fcol] = a.x + a.y;
        }
    }
    __syncthreads();

    // scores + masked softmax over W=4
    if (tid < 64) {
        int p = tid >> 2, w = tid & 3;
        const f2* cr = (const f2*)&catl[p * 426 + w * 106];
        const f2* vr = (const f2*)&vv[p * 110];
        f2 a{0.f, 0.f};
#pragma unroll
        for (int ff = 0; ff < 52; ++ff) a = fma2(cr[ff], vr[ff], a);
        float sc = a.x + a.y + vv[p * 110 + 104];
        if (lmask[(bl0 + p) * 4 + w] == 0) sc = -1e9f;
        float mx = fmaxf(sc, __shfl_xor(sc, 1, 64)); mx = fmaxf(mx, __shfl_xor(mx, 2, 64));
        float e = __expf(sc - mx);
        float ss = e + __shfl_xor(e, 1, 64); ss += __shfl_xor(ss, 2, 64);
        wts[tid] = e * __builtin_amdgcn_rcpf(ss);
    }
    __syncthreads();

    // att -> out[...,100:204]
    for (int e = tid; e < 1664; e += 256) {
        int p = e / 104, f = e % 104;
        const float* cp = &catl[p * 426 + f];
        float a = wts[p * 4] * cp[0] + wts[p * 4 + 1] * cp[106]
                + wts[p * 4 + 2] * cp[212] + wts[p * 4 + 3] * cp[318];
        out[(bl0 + p) * 204 + 100 + f] = a;
    }
}

extern "C" void kernel_launch(void* const* d_in, const int* in_sizes, int n_in,
                              void* d_out, int out_size, void* d_ws, size_t ws_size,
                              hipStream_t stream) {
    const int*   ids   = (const int*)d_in[0];
    const float* lex   = (const float*)d_in[1];
    const int*   pids  = (const int*)d_in[2];
    const int*   bmes  = (const int*)d_in[3];
    const int*   lmask = (const int*)d_in[4];
    const float* tokt  = (const float*)d_in[6];
    const float* pint  = (const float*)d_in[7];
    const float* wihf  = (const float*)d_in[8];
    const float* whhf  = (const float*)d_in[9];
    const float* bihf  = (const float*)d_in[10];
    const float* bhhf  = (const float*)d_in[11];
    const float* wihb  = (const float*)d_in[12];
    const float* whhb  = (const float*)d_in[13];
    const float* bihb  = (const float*)d_in[14];
    const float* bhhb  = (const float*)d_in[15];
    const float* wp    = (const float*)d_in[16];
    const float* bp    = (const float*)d_in[17];
    float* out = (float*)d_out;

    const size_t need = (size_t)2 * XGN * sizeof(_Float16);   // 52,428,800 B
    if (ws_size >= need) {
        _Float16* xg = (_Float16*)d_ws;
        xg_gemm<<<2048, 256, 0, stream>>>(ids, tokt, wihf, wihb, xg);
        lstm4<<<128, 512, 0, stream>>>(xg, whhf, bihf, bhhf, whhb, bihb, bhhb, out);
    } else {
        lstm_fb<<<128, 256, 0, stream>>>(ids, tokt, wihf, whhf, bihf, bhhf,
                                         wihb, whhb, bihb, bhhb, out);
    }
    attn3<<<2048, 256, 0, stream>>>(lex, pids, bmes, lmask, pint, wp, bp, out);
}